// Round 8
// baseline (549.430 us; speedup 1.0000x reference)
//
#include <hip/hip_runtime.h>

// 3-layer GCN (DGL GraphConv norm='both'), N=50000, E=800000, feats 1->100->10->1.
// Round 8: r7 proved the 40us fills are the harness's 256MB d_ws poison OUTSIDE
// the timed graph; cross-round deltas imply ~8us per-dispatch overhead => our
// 6-dispatch chain was ~45us of overhead on ~30us of work. This round fuses
// everything into ONE persistent kernel (512 blocks, guaranteed co-resident:
// needs 2/CU, launch_bounds+28KB LDS give >=4/CU) with device-scope spin grid
// barriers. CSR build uses deterministic [block][bucket][48] segmented arenas
// (zero global atomics). Only k_zero (6 barrier words) remains separate, since
// d_ws is poisoned 0xAA before timing.

#define NT 256
#define GRID 512
#define K_BKT 250      // node buckets
#define R_NODES 200    // nodes per bucket
#define SEG 48         // arena slots per (bin-block, bucket); mean 16.3, P(>48)~1e-10
#define CAP 4096       // csr entries per bucket; mean 3200, +15.8 sigma
#define CHUNK 4096     // edges per bin block
#define BIN_BLOCKS 196 // ceil(800000/4096)

__global__ void k_zero(unsigned* __restrict__ p) {
  if (threadIdx.x < 8) p[threadIdx.x] = 0u;
}

struct BinLds { unsigned cnt_d[K_BKT], cnt_s[K_BKT]; };
struct BktLds {
  unsigned cnt[R_NODES], cnts[R_NODES], start[R_NODES], cur[R_NODES];
  unsigned sc[NT];
  unsigned short crow_d[BIN_BLOCKS], crow_s[BIN_BLOCKS];
  unsigned nload;
  unsigned buf[CAP];           // compacted dst-keyed entries (16KB)
  unsigned short stage[CAP];   // per-node-sorted srclocal (8KB)
};
struct MlpLds { float W0s[100], b0s[100], W1s[1000]; };
union Pool { BinLds bin; BktLds bkt; MlpLds mlp; };

// Device-scope grid barrier. All GRID blocks must be co-resident (they are:
// need 2/CU, resources allow 4/CU). Counters pre-zeroed by k_zero each call.
__device__ __forceinline__ void grid_bar(unsigned* bar) {
  __threadfence();               // release: this thread's global writes
  __syncthreads();               // whole block's fences done
  if (threadIdx.x == 0) {
    atomicAdd(bar, 1u);          // device-scope
    while (__hip_atomic_load(bar, __ATOMIC_RELAXED, __HIP_MEMORY_SCOPE_AGENT) < GRID)
      __builtin_amdgcn_s_sleep(2);
  }
  __syncthreads();
  __threadfence();               // acquire: invalidate stale lines
}

__global__ __launch_bounds__(NT, 4) void k_mega(
    const int4* __restrict__ src4, const int4* __restrict__ dst4, int E4, int nbin,
    const float* __restrict__ x,
    const float* __restrict__ W0, const float* __restrict__ b0,
    const float* __restrict__ W1, const float* __restrict__ b1,
    const float* __restrict__ W2, const float* __restrict__ b2,
    unsigned* __restrict__ bar,
    unsigned short* __restrict__ cntd16, unsigned short* __restrict__ cnts16,
    unsigned* __restrict__ dstSeg, unsigned short* __restrict__ srcSeg,
    unsigned short* __restrict__ csr16,
    unsigned* __restrict__ rs, unsigned* __restrict__ rd,
    float* __restrict__ dsrc_inv, float* __restrict__ ddst_inv,
    float* __restrict__ s0, float* __restrict__ t1, float* __restrict__ t2,
    float* __restrict__ out, int n) {
  __shared__ Pool sp;
  const int t = threadIdx.x;
  const int blk = blockIdx.x;
  const int gsz = GRID * NT;

  // ---- phase 1: bin edges into [block][bucket][SEG] arenas (LDS atomics only)
  if (blk < nbin) {
    for (int k = t; k < K_BKT; k += NT) { sp.bin.cnt_d[k] = 0u; sp.bin.cnt_s[k] = 0u; }
    __syncthreads();
    int base4 = blk * (CHUNK / 4);
    int4 sA[4], dA[4];
#pragma unroll
    for (int j = 0; j < 4; j++) {
      int e4 = base4 + j * NT + t;
      if (e4 < E4) { sA[j] = src4[e4]; dA[j] = dst4[e4]; }
      else { sA[j] = make_int4(-1, -1, -1, -1); dA[j] = make_int4(-1, -1, -1, -1); }
    }
    const int* sp_ = (const int*)sA;
    const int* dp_ = (const int*)dA;
#pragma unroll
    for (int j = 0; j < 16; j++) {
      int d = dp_[j], s = sp_[j];
      if (d >= 0) {
        unsigned bd = (unsigned)d / R_NODES;
        unsigned pd = atomicAdd(&sp.bin.cnt_d[bd], 1u);
        if (pd < SEG)
          dstSeg[((size_t)blk * K_BKT + bd) * SEG + pd] =
              (unsigned)s | (((unsigned)d - bd * R_NODES) << 16);
        unsigned bs = (unsigned)s / R_NODES;
        unsigned ps = atomicAdd(&sp.bin.cnt_s[bs], 1u);
        if (ps < SEG)
          srcSeg[((size_t)blk * K_BKT + bs) * SEG + ps] =
              (unsigned short)((unsigned)s - bs * R_NODES);
      }
    }
    __syncthreads();
    for (int k = t; k < K_BKT; k += NT) {
      unsigned cd = sp.bin.cnt_d[k]; if (cd > SEG) cd = SEG;
      unsigned cs = sp.bin.cnt_s[k]; if (cs > SEG) cs = SEG;
      cntd16[(size_t)blk * K_BKT + k] = (unsigned short)cd;
      cnts16[(size_t)blk * K_BKT + k] = (unsigned short)cs;
    }
  }
  grid_bar(bar + 0);

  // ---- phase 2: per-bucket CSR + degrees + fused norm
  if (blk < K_BKT) {
    const int b = blk;
    for (int k = t; k < R_NODES; k += NT) { sp.bkt.cnt[k] = 0u; sp.bkt.cnts[k] = 0u; }
    if (t == 0) sp.bkt.nload = 0u;
    for (int i = t; i < BIN_BLOCKS; i += NT) {
      sp.bkt.crow_d[i] = (i < nbin) ? cntd16[(size_t)i * K_BKT + b] : (unsigned short)0;
      sp.bkt.crow_s[i] = (i < nbin) ? cnts16[(size_t)i * K_BKT + b] : (unsigned short)0;
    }
    __syncthreads();
    for (int sl = t; sl < BIN_BLOCKS * SEG; sl += NT) {
      int blkI = sl / SEG, idx = sl - blkI * SEG;
      if (idx < (int)sp.bkt.crow_d[blkI]) {
        unsigned e = dstSeg[((size_t)blkI * K_BKT + b) * SEG + idx];
        atomicAdd(&sp.bkt.cnt[e >> 16], 1u);
        unsigned p = atomicAdd(&sp.bkt.nload, 1u);
        if (p < CAP) sp.bkt.buf[p] = e;
      }
      if (idx < (int)sp.bkt.crow_s[blkI]) {
        unsigned short sl16 = srcSeg[((size_t)blkI * K_BKT + b) * SEG + idx];
        atomicAdd(&sp.bkt.cnts[sl16], 1u);
      }
    }
    __syncthreads();
    unsigned nd = sp.bkt.nload; if (nd > CAP) nd = CAP;
    unsigned v = (t < R_NODES) ? sp.bkt.cnt[t] : 0u;
    sp.bkt.sc[t] = v;
    __syncthreads();
    for (int off = 1; off < NT; off <<= 1) {
      unsigned a = (t >= off) ? sp.bkt.sc[t - off] : 0u;
      __syncthreads();
      sp.bkt.sc[t] += a;
      __syncthreads();
    }
    if (t < R_NODES) {
      unsigned st = sp.bkt.sc[t] - v;
      sp.bkt.start[t] = st;
      sp.bkt.cur[t] = st;
      int vg = b * R_NODES + t;                 // < n by construction
      unsigned di = sp.bkt.cnt[t], dou = sp.bkt.cnts[t];
      rs[vg] = (unsigned)b * CAP + st;
      rd[vg] = di;
      ddst_inv[vg] = rsqrtf((float)(di < 1u ? 1u : di));
      float ia = rsqrtf((float)(dou < 1u ? 1u : dou));
      dsrc_inv[vg] = ia;
      s0[vg] = x[vg] * ia;
    }
    __syncthreads();
    for (unsigned i = t; i < nd; i += NT) {
      unsigned e = sp.bkt.buf[i];
      unsigned pos = atomicAdd(&sp.bkt.cur[e >> 16], 1u);
      if (pos < CAP) sp.bkt.stage[pos] = (unsigned short)(e & 0xFFFFu);
    }
    __syncthreads();
    for (unsigned i = t; i < nd; i += NT) csr16[(size_t)b * CAP + i] = sp.bkt.stage[i];
  }
  grid_bar(bar + 1);

  // ---- phase 3: gather s0 + L0 epilogue (lrelu) + 100x10 matmul -> t1
  for (int k = t; k < 100; k += NT) { sp.mlp.W0s[k] = W0[k]; sp.mlp.b0s[k] = b0[k]; }
  for (int k = t; k < 1000; k += NT) sp.mlp.W1s[k] = W1[k];
  __syncthreads();
  for (int wi = blk * NT + t; wi < 4 * n; wi += gsz) {
    int v = wi >> 2, k4 = wi & 3;
    unsigned base = rs[v], deg = rd[v];
    const unsigned short* row = csr16 + base;
    float c = 0.0f;
    for (unsigned i = k4; i < deg; i += 4) c += s0[row[i]];
    c += __shfl_xor(c, 1, 4);
    c += __shfl_xor(c, 2, 4);
    c *= ddst_inv[v];
    float tt[10];
#pragma unroll
    for (int j = 0; j < 10; j++) tt[j] = 0.0f;
    for (int f = k4; f < 100; f += 4) {
      float a = c * sp.mlp.W0s[f] + sp.mlp.b0s[f];
      a = a >= 0.0f ? a : 0.01f * a;  // leaky_relu(0.01)
#pragma unroll
      for (int j = 0; j < 10; j++) tt[j] += a * sp.mlp.W1s[f * 10 + j];
    }
#pragma unroll
    for (int j = 0; j < 10; j++) {
      tt[j] += __shfl_xor(tt[j], 1, 4);
      tt[j] += __shfl_xor(tt[j], 2, 4);
    }
    float so = dsrc_inv[v];
    for (int j = k4; j < 10; j += 4) t1[v * 10 + j] = tt[j] * so;
  }
  grid_bar(bar + 2);

  // ---- phase 4: 10-wide gather of t1 + L1 epilogue (relu) + W2 dot -> t2
  {
    float w2f = 0.0f, b1f = 0.0f;
    for (int wi = blk * NT + t; wi < 16 * n; wi += gsz) {
      int v = wi >> 4, f = wi & 15;
      if (f < 10) { b1f = b1[f]; w2f = W2[f]; }
      unsigned base = rs[v], deg = rd[v];
      const unsigned short* row = csr16 + base;
      int r0 = row[f], r1 = row[f + 16], r2 = row[f + 32];  // csr16 padded +64
      float acc = 0.0f;
      for (unsigned i = 0; i < deg; i++) {
        int sv;
        if (i < 48u) {
          int which = i >> 4;
          int rsel = (which == 0) ? r0 : ((which == 1) ? r1 : r2);
          sv = __shfl(rsel, (int)(i & 15u), 16);
        } else {
          sv = row[i];
        }
        if (f < 10) acc += t1[(unsigned)sv * 10 + f];
      }
      float p = 0.0f;
      if (f < 10) {
        float h = acc * ddst_inv[v] + b1f;
        h = h > 0.0f ? h : 0.0f;  // relu
        p = h * w2f;
      }
      p += __shfl_xor(p, 1, 16);
      p += __shfl_xor(p, 2, 16);
      p += __shfl_xor(p, 4, 16);
      p += __shfl_xor(p, 8, 16);
      if (f == 0) t2[v] = p * dsrc_inv[v];
    }
  }
  grid_bar(bar + 3);

  // ---- phase 5: gather t2 + final epilogue -> out
  for (int wi = blk * NT + t; wi < 4 * n; wi += gsz) {
    int v = wi >> 2, k4 = wi & 3;
    unsigned base = rs[v], deg = rd[v];
    const unsigned short* row = csr16 + base;
    float c = 0.0f;
    for (unsigned i = k4; i < deg; i += 4) c += t2[row[i]];
    c += __shfl_xor(c, 1, 4);
    c += __shfl_xor(c, 2, 4);
    if (k4 == 0) {
      float h = c * ddst_inv[v] + b2[0];
      out[v] = h > 0.0f ? h : 0.0f;
    }
  }
}

extern "C" void kernel_launch(void* const* d_in, const int* in_sizes, int n_in,
                              void* d_out, int out_size, void* d_ws, size_t ws_size,
                              hipStream_t stream) {
  const float* in_feat = (const float*)d_in[0];
  const int* ei = (const int*)d_in[1];
  const float* W0 = (const float*)d_in[2];
  const float* b0 = (const float*)d_in[3];
  const float* W1 = (const float*)d_in[4];
  const float* b1 = (const float*)d_in[5];
  const float* W2 = (const float*)d_in[6];
  const float* b2 = (const float*)d_in[7];
  float* out = (float*)d_out;

  const int n = in_sizes[0];      // 50000 (= K_BKT * R_NODES)
  const int E = in_sizes[1] / 2;  // 800000 (divisible by 4)
  const int* src = ei;
  const int* dst = ei + E;
  const int E4 = E / 4;
  int nbin = (E + CHUNK - 1) / CHUNK;          // 196
  if (nbin > BIN_BLOCKS) nbin = BIN_BLOCKS;    // sized for this problem

  // Workspace layout. Only bar[8] needs zeroing (d_ws arrives poisoned 0xAA).
  unsigned* bar = (unsigned*)d_ws;                                    // 8
  unsigned short* cntd16 = (unsigned short*)(bar + 8);                // 196*250 u16
  unsigned short* cnts16 = cntd16 + (size_t)BIN_BLOCKS * K_BKT;       // 196*250 u16
  unsigned* dstSeg = (unsigned*)(cnts16 + (size_t)BIN_BLOCKS * K_BKT);// 196*250*48 u32
  unsigned short* srcSeg = (unsigned short*)(dstSeg + (size_t)BIN_BLOCKS * K_BKT * SEG);
  unsigned short* csr16 = srcSeg + (size_t)BIN_BLOCKS * K_BKT * SEG;  // 250*4096+64 u16
  unsigned* rs = (unsigned*)(csr16 + (size_t)K_BKT * CAP + 64);       // n
  unsigned* rd = rs + n;                                              // n
  float* dsrc_inv = (float*)(rd + n);                                 // n
  float* ddst_inv = dsrc_inv + n;                                     // n
  float* s0 = ddst_inv + n;                                           // n
  float* t1 = s0 + n;                                                 // 10n
  float* t2 = t1 + 10 * n;                                            // n

  k_zero<<<1, 64, 0, stream>>>(bar);
  k_mega<<<GRID, NT, 0, stream>>>((const int4*)src, (const int4*)dst, E4, nbin,
                                  in_feat, W0, b0, W1, b1, W2, b2,
                                  bar, cntd16, cnts16, dstSeg, srcSeg, csr16,
                                  rs, rd, dsrc_inv, ddst_inv, s0, t1, t2, out, n);
}

// Round 9
// 90.813 us; speedup vs baseline: 6.0501x; 6.0501x over previous
//
#include <hip/hip_runtime.h>

// 3-layer GCN (DGL GraphConv norm='both'), N=50000, E=800000, feats 1->100->10->1.
// Round 9: revert r8's persistent kernel (grid barriers cost ~100us+ each on
// gfx950 - device fences force cross-XCD L2 writebacks). Back to r7's 5-stage
// pipeline (~2us/dispatch measured overhead), minus work:
//  - deterministic [block][bucket][48] segmented binning (r8 phase1, proven
//    correct): zero global atomics, no cursors, k_zero dispatch eliminated.
//  - L0+L1 collapsed to exact piecewise-linear form: t1 = (c0*A[seg]+B[seg])
//    * dsrc_inv, with 101-segment tables precomputed by an extra block in
//    k_bucket (breakpoints of the 100 leaky-relus in the scalar c0).

#define NT 256
#define K_BKT 250      // node buckets
#define R_NODES 200    // nodes per bucket
#define SEG 48         // slots per (bin-block,bucket); mean 16.3, P(>48)~1e-10
#define CAP 4096       // csr entries per bucket; mean 3200, +15.8 sigma
#define CHUNK 4096     // edges per bin block
#define BIN_BLOCKS 196 // ceil(800000/4096)
#define FINF 3.0e38f

// -------- pass 1: bin edges into [block][bucket][SEG] arenas (LDS atomics) ---

__global__ __launch_bounds__(NT) void k_bin(const int4* __restrict__ src4,
                                            const int4* __restrict__ dst4, int E4,
                                            unsigned short* __restrict__ cntd16,
                                            unsigned short* __restrict__ cnts16,
                                            unsigned* __restrict__ dstSeg,
                                            unsigned short* __restrict__ srcSeg) {
  __shared__ unsigned cnt_d[K_BKT], cnt_s[K_BKT];
  int t = threadIdx.x, blk = blockIdx.x;
  for (int k = t; k < K_BKT; k += NT) { cnt_d[k] = 0u; cnt_s[k] = 0u; }
  __syncthreads();
  int base4 = blk * (CHUNK / 4);
  int4 sA[4], dA[4];
#pragma unroll
  for (int j = 0; j < 4; j++) {
    int e4 = base4 + j * NT + t;
    if (e4 < E4) { sA[j] = src4[e4]; dA[j] = dst4[e4]; }
    else { sA[j] = make_int4(-1, -1, -1, -1); dA[j] = make_int4(-1, -1, -1, -1); }
  }
  const int* sp = (const int*)sA;
  const int* dp = (const int*)dA;
#pragma unroll
  for (int j = 0; j < 16; j++) {
    int d = dp[j], s = sp[j];
    if (d >= 0) {
      unsigned bd = (unsigned)d / R_NODES;
      unsigned pd = atomicAdd(&cnt_d[bd], 1u);
      if (pd < SEG)
        dstSeg[((size_t)blk * K_BKT + bd) * SEG + pd] =
            (unsigned)s | (((unsigned)d - bd * R_NODES) << 16);
      unsigned bs = (unsigned)s / R_NODES;
      unsigned ps = atomicAdd(&cnt_s[bs], 1u);
      if (ps < SEG)
        srcSeg[((size_t)blk * K_BKT + bs) * SEG + ps] =
            (unsigned short)((unsigned)s - bs * R_NODES);
    }
  }
  __syncthreads();
  for (int k = t; k < K_BKT; k += NT) {
    unsigned cd = cnt_d[k]; if (cd > SEG) cd = SEG;
    unsigned cs = cnt_s[k]; if (cs > SEG) cs = SEG;
    cntd16[(size_t)blk * K_BKT + k] = (unsigned short)cd;
    cnts16[(size_t)blk * K_BKT + k] = (unsigned short)cs;
  }
}

// -------- pass 2: per-bucket CSR + degrees + norm; block 250 = PWL tables ----

struct BktLds {
  unsigned cnt[R_NODES], cnts[R_NODES], cur[R_NODES];
  unsigned sc[NT];
  unsigned short crow_d[NT], crow_s[NT];
  unsigned off_d[NT];
  unsigned buf[CAP];
  unsigned short stage[CAP];
};
struct PreLds { float beta[128]; int ord[128]; };
union BPool { BktLds b; PreLds p; };

__global__ __launch_bounds__(NT) void k_bucket(
    const unsigned short* __restrict__ cntd16, const unsigned short* __restrict__ cnts16,
    const unsigned* __restrict__ dstSeg, const unsigned short* __restrict__ srcSeg,
    const float* __restrict__ x,
    const float* __restrict__ W0, const float* __restrict__ b0,
    const float* __restrict__ W1,
    float* __restrict__ betas, float* __restrict__ Aseg, float* __restrict__ Bseg,
    unsigned short* __restrict__ csr16,
    unsigned* __restrict__ rs, unsigned* __restrict__ rd,
    float* __restrict__ dsrc_inv, float* __restrict__ ddst_inv,
    float* __restrict__ s0, int n, int nbin) {
  __shared__ BPool u;
  int t = threadIdx.x, blk = blockIdx.x;
  if (blk < K_BKT) {
    const int b = blk;
    for (int k = t; k < R_NODES; k += NT) { u.b.cnt[k] = 0u; u.b.cnts[k] = 0u; }
    u.b.crow_d[t] = (t < nbin) ? cntd16[(size_t)t * K_BKT + b] : (unsigned short)0;
    u.b.crow_s[t] = (t < nbin) ? cnts16[(size_t)t * K_BKT + b] : (unsigned short)0;
    __syncthreads();
    // scan bin-block counts -> arena offsets
    unsigned cv = u.b.crow_d[t];
    u.b.sc[t] = cv;
    __syncthreads();
    for (int off = 1; off < NT; off <<= 1) {
      unsigned a = (t >= off) ? u.b.sc[t - off] : 0u;
      __syncthreads();
      u.b.sc[t] += a;
      __syncthreads();
    }
    u.b.off_d[t] = u.b.sc[t] - cv;
    __syncthreads();
    unsigned nd = u.b.off_d[NT - 1];  // crow_d[255]=0 -> exclusive@255 == total
    if (nd > CAP) nd = CAP;
    // load segments: histogram + deterministic compaction
    for (int sl = t; sl < BIN_BLOCKS * SEG; sl += NT) {
      int blkI = sl / SEG, idx = sl - blkI * SEG;
      if (idx < (int)u.b.crow_d[blkI]) {
        unsigned e = dstSeg[((size_t)blkI * K_BKT + b) * SEG + idx];
        atomicAdd(&u.b.cnt[e >> 16], 1u);
        unsigned o = u.b.off_d[blkI] + (unsigned)idx;
        if (o < CAP) u.b.buf[o] = e;
      }
      if (idx < (int)u.b.crow_s[blkI])
        atomicAdd(&u.b.cnts[srcSeg[((size_t)blkI * K_BKT + b) * SEG + idx]], 1u);
    }
    __syncthreads();
    // node-level scan -> row starts; fused degree norm + s0
    unsigned v = (t < R_NODES) ? u.b.cnt[t] : 0u;
    u.b.sc[t] = v;
    __syncthreads();
    for (int off = 1; off < NT; off <<= 1) {
      unsigned a = (t >= off) ? u.b.sc[t - off] : 0u;
      __syncthreads();
      u.b.sc[t] += a;
      __syncthreads();
    }
    if (t < R_NODES) {
      unsigned st = u.b.sc[t] - v;
      int vg = b * R_NODES + t;
      if (vg < n) {
        unsigned di = u.b.cnt[t], dou = u.b.cnts[t];
        rs[vg] = (unsigned)b * CAP + st;
        rd[vg] = di;
        ddst_inv[vg] = rsqrtf((float)(di < 1u ? 1u : di));
        float ia = rsqrtf((float)(dou < 1u ? 1u : dou));
        dsrc_inv[vg] = ia;
        s0[vg] = x[vg] * ia;
      }
      u.b.cur[t] = st;
    }
    __syncthreads();
    for (unsigned i = t; i < nd; i += NT) {
      unsigned e = u.b.buf[i];
      unsigned pos = atomicAdd(&u.b.cur[e >> 16], 1u);
      if (pos < CAP) u.b.stage[pos] = (unsigned short)(e & 0xFFFFu);
    }
    __syncthreads();
    for (unsigned i = t; i < nd; i += NT) csr16[(size_t)b * CAP + i] = u.b.stage[i];
  } else {
    // ---- PWL precompute: t1(c0)[j] = c0*A[seg][j] + B[seg][j] (exact) ----
    if (t < 128) { u.p.beta[t] = FINF; u.p.ord[t] = t; }
    if (t < 100) {
      float w = W0[t];
      u.p.beta[t] = (w != 0.0f) ? (-b0[t] / w) : FINF;
    }
    __syncthreads();
    for (int p = 0; p < 100; p++) {  // odd-even transposition sort (key, idx)
      if (t + 1 < 100 && ((t & 1) == (p & 1))) {
        float a = u.p.beta[t], bb = u.p.beta[t + 1];
        if (bb < a) {
          u.p.beta[t] = bb; u.p.beta[t + 1] = a;
          int tmp = u.p.ord[t]; u.p.ord[t] = u.p.ord[t + 1]; u.p.ord[t + 1] = tmp;
        }
      }
      __syncthreads();
    }
    if (t < 128) betas[t] = u.p.beta[t];
    if (t < 10) {
      const int j = t;
      float a = 0.0f, bacc = 0.0f;
      for (int f = 0; f < 100; f++) {  // state at c0 = -inf
        float w = W0[f], bb = b0[f], w1 = W1[f * 10 + j];
        if (w == 0.0f) {
          float h = bb >= 0.0f ? bb : 0.01f * bb;
          bacc += h * w1;
        } else {
          float cc = (w > 0.0f) ? 0.01f : 1.0f;
          a += cc * w * w1;
          bacc += cc * bb * w1;
        }
      }
      Aseg[j] = a; Bseg[j] = bacc;
      for (int k = 0; k < 100; k++) {  // walk breakpoints in sorted order
        int f = u.p.ord[k];
        float w = W0[f];
        if (w != 0.0f) {
          float w1 = W1[f * 10 + j];
          a += 0.99f * fabsf(w) * w1;
          bacc += 0.99f * ((w > 0.0f) ? 1.0f : -1.0f) * b0[f] * w1;
        }
        Aseg[(k + 1) * 10 + j] = a;
        Bseg[(k + 1) * 10 + j] = bacc;
      }
    }
  }
}

// -------- fused gather + compute stages (all atomic-free) --------

// 4 lanes/node: gather c0, then t1 = (c0*A[seg]+B[seg]) * dsrc_inv via PWL.
__global__ void k_g_l0l1(const unsigned* __restrict__ rs, const unsigned* __restrict__ rd,
                         const unsigned short* __restrict__ csr16,
                         const float* __restrict__ s0,
                         const float* __restrict__ dsrc_inv, const float* __restrict__ ddst_inv,
                         const float* __restrict__ betas,
                         const float* __restrict__ Aseg, const float* __restrict__ Bseg,
                         float* __restrict__ t1, int n) {
  __shared__ float bs_[128], As[1010], Bs[1010];
  for (int k = threadIdx.x; k < 128; k += blockDim.x) bs_[k] = betas[k];
  for (int k = threadIdx.x; k < 1010; k += blockDim.x) { As[k] = Aseg[k]; Bs[k] = Bseg[k]; }
  __syncthreads();
  int tid = blockIdx.x * blockDim.x + threadIdx.x;
  int v = tid >> 2, k4 = tid & 3;
  if (v >= n) return;
  unsigned base = rs[v], deg = rd[v];
  const unsigned short* row = csr16 + base;
  float c = 0.0f;
#pragma unroll 4
  for (unsigned i = k4; i < deg; i += 4) c += s0[row[i]];
  c += __shfl_xor(c, 1, 4);
  c += __shfl_xor(c, 2, 4);
  float c0 = c * ddst_inv[v];
  int lo = 0, hi = 100;  // seg = #{beta_sorted < c0}
#pragma unroll
  for (int it = 0; it < 7; it++) {
    int mid = (lo + hi) >> 1;
    bool go = bs_[mid] < c0;
    lo = go ? mid + 1 : lo;
    hi = go ? hi : mid;
  }
  float so = dsrc_inv[v];
  for (int j = k4; j < 10; j += 4)
    t1[v * 10 + j] = fmaf(c0, As[lo * 10 + j], Bs[lo * 10 + j]) * so;
}

// 16 lanes/node (10 active): gather t1 rows + L1 epilogue + W2 dot -> t2.
__global__ void k_g10_l1l2(const unsigned* __restrict__ rs, const unsigned* __restrict__ rd,
                           const unsigned short* __restrict__ csr16,
                           const float* __restrict__ t1,
                           const float* __restrict__ dsrc_inv, const float* __restrict__ ddst_inv,
                           const float* __restrict__ b1, const float* __restrict__ W2,
                           float* __restrict__ t2, int n) {
  int tid = blockIdx.x * blockDim.x + threadIdx.x;
  int v = tid >> 4, f = tid & 15;
  if (v >= n) return;
  unsigned base = rs[v], deg = rd[v];
  const unsigned short* row = csr16 + base;
  int r0 = row[f], r1 = row[f + 16], r2 = row[f + 32];  // csr16 padded +64
  float acc = 0.0f;
  for (unsigned i = 0; i < deg; i++) {
    int sv;
    if (i < 48u) {
      int which = i >> 4;
      int rsel = (which == 0) ? r0 : ((which == 1) ? r1 : r2);
      sv = __shfl(rsel, (int)(i & 15u), 16);
    } else {
      sv = row[i];  // astronomically rare
    }
    if (f < 10) acc += t1[(unsigned)sv * 10 + f];
  }
  float p = 0.0f;
  if (f < 10) {
    float h = acc * ddst_inv[v] + b1[f];
    h = h > 0.0f ? h : 0.0f;  // relu
    p = h * W2[f];
  }
  p += __shfl_xor(p, 1, 16);
  p += __shfl_xor(p, 2, 16);
  p += __shfl_xor(p, 4, 16);
  p += __shfl_xor(p, 8, 16);
  if (f == 0) t2[v] = p * dsrc_inv[v];
}

// 4 lanes/node: gather t2 + final epilogue.
__global__ void k_g_out(const unsigned* __restrict__ rs, const unsigned* __restrict__ rd,
                        const unsigned short* __restrict__ csr16,
                        const float* __restrict__ t2, const float* __restrict__ ddst_inv,
                        const float* __restrict__ b2, float* __restrict__ out, int n) {
  int tid = blockIdx.x * blockDim.x + threadIdx.x;
  int v = tid >> 2, k4 = tid & 3;
  if (v >= n) return;
  unsigned base = rs[v], deg = rd[v];
  const unsigned short* row = csr16 + base;
  float c = 0.0f;
#pragma unroll 4
  for (unsigned i = k4; i < deg; i += 4) c += t2[row[i]];
  c += __shfl_xor(c, 1, 4);
  c += __shfl_xor(c, 2, 4);
  if (k4 == 0) {
    float h = c * ddst_inv[v] + b2[0];
    out[v] = h > 0.0f ? h : 0.0f;
  }
}

extern "C" void kernel_launch(void* const* d_in, const int* in_sizes, int n_in,
                              void* d_out, int out_size, void* d_ws, size_t ws_size,
                              hipStream_t stream) {
  const float* in_feat = (const float*)d_in[0];
  const int* ei = (const int*)d_in[1];
  const float* W0 = (const float*)d_in[2];
  const float* b0 = (const float*)d_in[3];
  const float* W1 = (const float*)d_in[4];
  const float* b1 = (const float*)d_in[5];
  const float* W2 = (const float*)d_in[6];
  const float* b2 = (const float*)d_in[7];
  float* out = (float*)d_out;

  const int n = in_sizes[0];      // 50000 (= K_BKT * R_NODES)
  const int E = in_sizes[1] / 2;  // 800000
  const int* src = ei;
  const int* dst = ei + E;
  const int E4 = E / 4;
  int nbin = (E + CHUNK - 1) / CHUNK;          // 196
  if (nbin > BIN_BLOCKS) nbin = BIN_BLOCKS;

  // Workspace layout. Nothing needs pre-zeroing: every word read was written
  // earlier in the same call (bin counts cover all [block][bucket] slots).
  unsigned short* cntd16 = (unsigned short*)d_ws;                     // 196*250
  unsigned short* cnts16 = cntd16 + (size_t)BIN_BLOCKS * K_BKT;       // 196*250
  unsigned* dstSeg = (unsigned*)(cnts16 + (size_t)BIN_BLOCKS * K_BKT);// 196*250*48
  unsigned short* srcSeg = (unsigned short*)(dstSeg + (size_t)BIN_BLOCKS * K_BKT * SEG);
  unsigned short* csr16 = srcSeg + (size_t)BIN_BLOCKS * K_BKT * SEG;  // 250*4096+64
  unsigned* rs = (unsigned*)(csr16 + (size_t)K_BKT * CAP + 64);       // n
  unsigned* rd = rs + n;                                              // n
  float* dsrc_inv = (float*)(rd + n);                                 // n
  float* ddst_inv = dsrc_inv + n;                                     // n
  float* s0 = ddst_inv + n;                                           // n
  float* t1 = s0 + n;                                                 // 10n
  float* t2 = t1 + 10 * n;                                            // n
  float* betas = t2 + n;                                              // 128
  float* Aseg = betas + 128;                                          // 1010
  float* Bseg = Aseg + 1010;                                          // 1010

  k_bin<<<nbin, NT, 0, stream>>>((const int4*)src, (const int4*)dst, E4,
                                 cntd16, cnts16, dstSeg, srcSeg);
  k_bucket<<<K_BKT + 1, NT, 0, stream>>>(cntd16, cnts16, dstSeg, srcSeg, in_feat,
                                         W0, b0, W1, betas, Aseg, Bseg, csr16,
                                         rs, rd, dsrc_inv, ddst_inv, s0, n, nbin);
  k_g_l0l1<<<(4 * n + NT - 1) / NT, NT, 0, stream>>>(rs, rd, csr16, s0, dsrc_inv, ddst_inv,
                                                     betas, Aseg, Bseg, t1, n);
  k_g10_l1l2<<<(16 * n + NT - 1) / NT, NT, 0, stream>>>(rs, rd, csr16, t1, dsrc_inv, ddst_inv,
                                                        b1, W2, t2, n);
  k_g_out<<<(4 * n + NT - 1) / NT, NT, 0, stream>>>(rs, rd, csr16, t2, ddst_inv, b2, out, n);
}